// Round 1
// baseline (3663.045 us; speedup 1.0000x reference)
//
#include <hip/hip_runtime.h>
#include <hip/hip_bf16.h>

#define Hh  512
#define Bb  64
#define Tt  256
#define G7  3584
#define NWG 128

typedef __attribute__((ext_vector_type(8))) short short8;
typedef __attribute__((ext_vector_type(4))) float f32x4;

// RNE float -> bf16 bits
static __device__ __forceinline__ unsigned short f2bf(float f) {
  unsigned int u = __float_as_uint(f);
  unsigned int lsb = (u >> 16) & 1u;
  u += 0x7fffu + lsb;
  return (unsigned short)(u >> 16);
}

static __device__ __forceinline__ float sigmoidf_(float x) {
  return 1.0f / (1.0f + expf(-x));
}
static __device__ __forceinline__ float softplusf_(float x) {
  return fmaxf(x, 0.0f) + log1pf(expf(-fabsf(x)));
}

// Pack W [1024][3584] f32 -> per-WG fragment-ready bf16:
// wp[((wg*32+kf)*2+nf)*64 + lane][8] = bf16(W[kf*32+(lane>>4)*8+i][col])
// col = g*512 + wg*4 + r, where pcol = nf*16 + (lane&15) = 4*g + r  (pcol>=28 -> 0)
__global__ void k_pack_w(const float* __restrict__ W, unsigned short* __restrict__ wp) {
  int t = blockIdx.x * 256 + threadIdx.x;            // 0 .. 524287
  int l  = t & 63;
  int nf = (t >> 6) & 1;
  int kf = (t >> 7) & 31;
  int wg = t >> 12;
  int pcol  = nf * 16 + (l & 15);
  int kbase = kf * 32 + (l >> 4) * 8;
  unsigned int o[4];
  if (pcol < 28) {
    int g = pcol >> 2, r = pcol & 3;
    int col = g * 512 + wg * 4 + r;
    const float* src = W + (size_t)kbase * G7 + col;
#pragma unroll
    for (int j = 0; j < 4; ++j) {
      unsigned short a = f2bf(src[(size_t)(2 * j) * G7]);
      unsigned short b = f2bf(src[(size_t)(2 * j + 1) * G7]);
      o[j] = (unsigned int)a | ((unsigned int)b << 16);
    }
  } else {
    o[0] = o[1] = o[2] = o[3] = 0u;
  }
  unsigned long long* q = (unsigned long long*)(wp + (size_t)t * 8);
  q[0] = (unsigned long long)o[0] | ((unsigned long long)o[1] << 32);
  q[1] = (unsigned long long)o[2] | ((unsigned long long)o[3] << 32);
}

// X [B][T][H] f32 -> xT [T][B][H] bf16
__global__ void k_xt(const float* __restrict__ X, unsigned short* __restrict__ xT) {
  int t = blockIdx.x * 256 + threadIdx.x;            // 0 .. 2097151
  int k4 = t & 127;
  int b  = (t >> 7) & 63;
  int tt = t >> 13;
  const float4* in = (const float4*)(X + ((size_t)(b * Tt + tt) * Hh + k4 * 4));
  float4 f = *in;
  unsigned int p0 = (unsigned)f2bf(f.x) | ((unsigned)f2bf(f.y) << 16);
  unsigned int p1 = (unsigned)f2bf(f.z) | ((unsigned)f2bf(f.w) << 16);
  unsigned long long v = (unsigned long long)p0 | ((unsigned long long)p1 << 32);
  *(unsigned long long*)(xT + ((size_t)(tt * Bb + b) * Hh + k4 * 4)) = v;
}

__global__ void k_init(unsigned int* __restrict__ z, int n) {
  for (int i = blockIdx.x * 256 + threadIdx.x; i < n; i += gridDim.x * 256) z[i] = 0u;
}

// Persistent recurrence: 128 WGs x 256 thr (4 waves). Wave w computes rows
// 16w..16w+15 (batches) x 32 cols (WG's gate-interleaved slice), K=1024
// (k<512: x_t, k>=512: h_{t-1}). Weights live in VGPRs for all 256 steps.
__global__ __launch_bounds__(256, 1) void k_seq(
    const unsigned short* __restrict__ wp,
    const unsigned short* __restrict__ xT,
    const float* __restrict__ bias,
    const float* __restrict__ dtime,
    unsigned short* __restrict__ hbuf,   // [2][64][512] bf16
    unsigned int* __restrict__ bar,
    float* __restrict__ out) {

  const int wg   = blockIdx.x;
  const int tid  = threadIdx.x;
  const int wave = tid >> 6;
  const int lane = tid & 63;

  __shared__ float g_lds[64 * 33];

  // persistent weight fragments: w[kf][nf], kf 0..15 = W_x, 16..31 = W_h
  short8 w[32][2];
  {
    const short8* base = reinterpret_cast<const short8*>(wp);
#pragma unroll
    for (int kf = 0; kf < 32; ++kf) {
#pragma unroll
      for (int nf = 0; nf < 2; ++nf) {
        w[kf][nf] = base[((size_t)(wg * 32 + kf) * 2 + nf) * 64 + lane];
      }
    }
  }

  const int eb   = tid >> 2;       // epilogue batch 0..63
  const int er   = tid & 3;        // epilogue j-offset 0..3
  const int jcol = wg * 4 + er;    // H index owned by this thread
  float bs[7];
#pragma unroll
  for (int g = 0; g < 7; ++g) bs[g] = bias[g * 512 + jcol];

  // A-fragment per-lane element offset within a [64][512] slab
  const int aoff = (wave * 16 + (lane & 15)) * 512 + (lane >> 4) * 8;

  float cf = 0.0f, cb = 0.0f;      // c_func, c_bar states for (eb, jcol)

  for (int t = 0; t < Tt; ++t) {
    f32x4 acc00 = {0.f, 0.f, 0.f, 0.f};
    f32x4 acc01 = {0.f, 0.f, 0.f, 0.f};
    f32x4 acc10 = {0.f, 0.f, 0.f, 0.f};
    f32x4 acc11 = {0.f, 0.f, 0.f, 0.f};

    // ---- x-phase (no dependency on other WGs; runs before the barrier wait)
    const unsigned short* xp = xT + (size_t)t * (Bb * Hh) + aoff;
#pragma unroll
    for (int kf = 0; kf < 16; ++kf) {
      short8 a = *reinterpret_cast<const short8*>(xp + kf * 32);
      if (kf & 1) {
        acc01 = __builtin_amdgcn_mfma_f32_16x16x32_bf16(a, w[kf][0], acc01, 0, 0, 0);
        acc11 = __builtin_amdgcn_mfma_f32_16x16x32_bf16(a, w[kf][1], acc11, 0, 0, 0);
      } else {
        acc00 = __builtin_amdgcn_mfma_f32_16x16x32_bf16(a, w[kf][0], acc00, 0, 0, 0);
        acc10 = __builtin_amdgcn_mfma_f32_16x16x32_bf16(a, w[kf][1], acc10, 0, 0, 0);
      }
    }

    // ---- wait until all WGs finished step t-1 (h_{t-1} fully published)
    if (t > 0) {
      if (tid == 0) {
        unsigned target = (unsigned)(t * NWG);
        int guard = 0;
        while (__hip_atomic_load(bar, __ATOMIC_RELAXED, __HIP_MEMORY_SCOPE_AGENT) < target) {
          if (++guard > (1 << 22)) break;   // bounded: wrong answer, never a hang
        }
        __threadfence();                    // acquire: invalidate stale h lines
      }
      __syncthreads();
    }

    // ---- h-phase
    const unsigned short* hp = hbuf + (size_t)((t & 1) ^ 1) * (Bb * Hh) + aoff;
#pragma unroll
    for (int kf = 0; kf < 16; ++kf) {
      short8 a = *reinterpret_cast<const short8*>(hp + kf * 32);
      if (kf & 1) {
        acc01 = __builtin_amdgcn_mfma_f32_16x16x32_bf16(a, w[16 + kf][0], acc01, 0, 0, 0);
        acc11 = __builtin_amdgcn_mfma_f32_16x16x32_bf16(a, w[16 + kf][1], acc11, 0, 0, 0);
      } else {
        acc00 = __builtin_amdgcn_mfma_f32_16x16x32_bf16(a, w[16 + kf][0], acc00, 0, 0, 0);
        acc10 = __builtin_amdgcn_mfma_f32_16x16x32_bf16(a, w[16 + kf][1], acc10, 0, 0, 0);
      }
    }

    // ---- publish raw gate pre-activations to LDS (D-frag: row=(l>>4)*4+q, col=l&15)
    {
      f32x4 s0 = acc00 + acc01;
      f32x4 s1 = acc10 + acc11;
      int colbase = lane & 15;
      int row0 = wave * 16 + (lane >> 4) * 4;
#pragma unroll
      for (int q = 0; q < 4; ++q) g_lds[(row0 + q) * 33 + colbase] = s0[q];
#pragma unroll
      for (int q = 0; q < 4; ++q) g_lds[(row0 + q) * 33 + 16 + colbase] = s1[q];
    }
    __syncthreads();

    // ---- epilogue: thread (eb, er) consumes its 7 gates
    float gv[7];
#pragma unroll
    for (int g = 0; g < 7; ++g) gv[g] = g_lds[eb * 33 + g * 4 + er] + bs[g];

    float gi  = sigmoidf_(gv[0]);
    float gf  = sigmoidf_(gv[1]);
    float go  = sigmoidf_(gv[2]);
    float gib = sigmoidf_(gv[3]);
    float gfb = sigmoidf_(gv[4]);
    float gd  = softplusf_(gv[5]);
    float zt  = tanhf(gv[6]);
    float dt  = dtime[eb * Tt + t];

    float c_t    = gf * cf + gi * zt;
    float cbar_t = gfb * cb + gib * zt;
    float cfn    = cbar_t + (c_t - cbar_t) * expf(-gd * dt);
    float h      = go * tanhf(cfn);
    cf = cfn;
    cb = cbar_t;

    size_t ho = (size_t)(eb * Tt + t) * Hh + jcol;
    out[ho] = h;
    size_t db = (size_t)8388608 + (size_t)((eb * Tt + t) * 4) * Hh + jcol;
    out[db]        = c_t;
    out[db + 512]  = cbar_t;
    out[db + 1024] = gd;
    out[db + 1536] = go;
    hbuf[(size_t)(t & 1) * (Bb * Hh) + eb * Hh + jcol] = f2bf(h);

    // ---- arrive (after __syncthreads drains all threads' stores)
    __syncthreads();
    if (tid == 0) {
      __threadfence();                     // release: flush h to coherence point
      __hip_atomic_fetch_add(bar, 1u, __ATOMIC_RELAXED, __HIP_MEMORY_SCOPE_AGENT);
    }
  }
}

extern "C" void kernel_launch(void* const* d_in, const int* in_sizes, int n_in,
                              void* d_out, int out_size, void* d_ws, size_t ws_size,
                              hipStream_t stream) {
  const float* X  = (const float*)d_in[0];   // [64][256][512]
  const float* dt = (const float*)d_in[1];   // [64][256]
  const float* W  = (const float*)d_in[2];   // [1024][3584]
  const float* bi = (const float*)d_in[3];   // [3584]
  float* out = (float*)d_out;

  char* ws = (char*)d_ws;
  unsigned short* wp   = (unsigned short*)(ws);             //  8,388,608 B
  unsigned short* xT   = (unsigned short*)(ws + 8388608);   // 16,777,216 B
  unsigned short* hb   = (unsigned short*)(ws + 25165824);  //    131,072 B
  unsigned int*  zbase = (unsigned int*)(ws + 25165824);    // hbuf + bar zero region
  unsigned int*  bar   = (unsigned int*)(ws + 25296896);    //          4 B

  k_pack_w<<<2048, 256, 0, stream>>>(W, wp);
  k_xt<<<8192, 256, 0, stream>>>(X, xT);
  k_init<<<64, 256, 0, stream>>>(zbase, 32769);
  k_seq<<<NWG, 256, 0, stream>>>(wp, xT, bi, dt, hb, bar, out);
}

// Round 2
// 2471.186 us; speedup vs baseline: 1.4823x; 1.4823x over previous
//
#include <hip/hip_runtime.h>
#include <hip/hip_bf16.h>

#define Hh  512
#define Bb  64
#define Tt  256
#define G7  3584
#define NWG 128

typedef __attribute__((ext_vector_type(8))) short short8;
typedef __attribute__((ext_vector_type(4))) float f32x4;

union U16 { unsigned long long q[2]; short8 v; };

// RNE float -> bf16 bits
static __device__ __forceinline__ unsigned short f2bf(float f) {
  unsigned int u = __float_as_uint(f);
  unsigned int lsb = (u >> 16) & 1u;
  u += 0x7fffu + lsb;
  return (unsigned short)(u >> 16);
}

static __device__ __forceinline__ float sigmoidf_(float x) {
  return 1.0f / (1.0f + expf(-x));
}
static __device__ __forceinline__ float softplusf_(float x) {
  return fmaxf(x, 0.0f) + log1pf(expf(-fabsf(x)));
}

// Pack W [1024][3584] f32 -> per-WG fragment-ready bf16:
// wp[((wg*32+kf)*2+nf)*64 + lane][8] = bf16(W[kf*32+(lane>>4)*8+i][col])
// col = g*512 + wg*4 + r, where pcol = nf*16 + (lane&15) = 4*g + r  (pcol>=28 -> 0)
__global__ void k_pack_w(const float* __restrict__ W, unsigned short* __restrict__ wp) {
  int t = blockIdx.x * 256 + threadIdx.x;            // 0 .. 524287
  int l  = t & 63;
  int nf = (t >> 6) & 1;
  int kf = (t >> 7) & 31;
  int wg = t >> 12;
  int pcol  = nf * 16 + (l & 15);
  int kbase = kf * 32 + (l >> 4) * 8;
  unsigned int o[4];
  if (pcol < 28) {
    int g = pcol >> 2, r = pcol & 3;
    int col = g * 512 + wg * 4 + r;
    const float* src = W + (size_t)kbase * G7 + col;
#pragma unroll
    for (int j = 0; j < 4; ++j) {
      unsigned short a = f2bf(src[(size_t)(2 * j) * G7]);
      unsigned short b = f2bf(src[(size_t)(2 * j + 1) * G7]);
      o[j] = (unsigned int)a | ((unsigned int)b << 16);
    }
  } else {
    o[0] = o[1] = o[2] = o[3] = 0u;
  }
  unsigned long long* q = (unsigned long long*)(wp + (size_t)t * 8);
  q[0] = (unsigned long long)o[0] | ((unsigned long long)o[1] << 32);
  q[1] = (unsigned long long)o[2] | ((unsigned long long)o[3] << 32);
}

// X [B][T][H] f32 -> xT [T][B][H] bf16
__global__ void k_xt(const float* __restrict__ X, unsigned short* __restrict__ xT) {
  int t = blockIdx.x * 256 + threadIdx.x;            // 0 .. 2097151
  int k4 = t & 127;
  int b  = (t >> 7) & 63;
  int tt = t >> 13;
  const float4* in = (const float4*)(X + ((size_t)(b * Tt + tt) * Hh + k4 * 4));
  float4 f = *in;
  unsigned int p0 = (unsigned)f2bf(f.x) | ((unsigned)f2bf(f.y) << 16);
  unsigned int p1 = (unsigned)f2bf(f.z) | ((unsigned)f2bf(f.w) << 16);
  unsigned long long v = (unsigned long long)p0 | ((unsigned long long)p1 << 32);
  *(unsigned long long*)(xT + ((size_t)(tt * Bb + b) * Hh + k4 * 4)) = v;
}

__global__ void k_init(unsigned int* __restrict__ z, int n) {
  for (int i = blockIdx.x * 256 + threadIdx.x; i < n; i += gridDim.x * 256) z[i] = 0u;
}

// Persistent recurrence: 128 WGs x 256 thr (4 waves). Wave w computes rows
// 16w..16w+15 (batches) x 32 cols (WG's gate-interleaved slice), K=1024
// (k<512: x_t, k>=512: h_{t-1}).
// Sync: fence-free. h exchanged via relaxed agent-scope (sc1) 8B atomics
// (write-through / L2-bypass, so L2 keeps the weight slices hot).
// Per-WG flag (64B stride) released after __syncthreads' vmcnt(0) drain;
// every wave polls all 128 flags independently (no tid0 spin, no extra bar).
__global__ __launch_bounds__(256, 1) void k_seq(
    const unsigned short* __restrict__ wp,
    const unsigned short* __restrict__ xT,
    const float* __restrict__ bias,
    const float* __restrict__ dtime,
    unsigned short* __restrict__ hbuf,   // [2][64][512] bf16
    unsigned int* __restrict__ flags,    // [128] stride-16 uints (64B apart)
    float* __restrict__ out) {

  const int wg   = blockIdx.x;
  const int tid  = threadIdx.x;
  const int wave = tid >> 6;
  const int lane = tid & 63;

  __shared__ float g_lds[64 * 33];

  // weight fragments: w[kf][nf], kf 0..15 = W_x, 16..31 = W_h (L2-streamed)
  short8 w[32][2];
  {
    const short8* base = reinterpret_cast<const short8*>(wp);
#pragma unroll
    for (int kf = 0; kf < 32; ++kf) {
#pragma unroll
      for (int nf = 0; nf < 2; ++nf) {
        w[kf][nf] = base[((size_t)(wg * 32 + kf) * 2 + nf) * 64 + lane];
      }
    }
  }

  const int eb   = tid >> 2;       // epilogue batch 0..63
  const int er   = tid & 3;        // epilogue j-offset 0..3
  const int jcol = wg * 4 + er;    // H index owned by this thread
  float bs[7];
#pragma unroll
  for (int g = 0; g < 7; ++g) bs[g] = bias[g * 512 + jcol];

  // A-fragment per-lane element offset within a [64][512] slab
  const int aoff = (wave * 16 + (lane & 15)) * 512 + (lane >> 4) * 8;

  const unsigned int* pf0 = flags + (size_t)lane * 16;
  const unsigned int* pf1 = flags + (size_t)(64 + lane) * 16;

  float cf = 0.0f, cb = 0.0f;      // c_func, c_bar states for (eb, jcol)

  for (int t = 0; t < Tt; ++t) {
    f32x4 acc00 = {0.f, 0.f, 0.f, 0.f};
    f32x4 acc01 = {0.f, 0.f, 0.f, 0.f};
    f32x4 acc10 = {0.f, 0.f, 0.f, 0.f};
    f32x4 acc11 = {0.f, 0.f, 0.f, 0.f};

    float dt = dtime[eb * Tt + t];   // issue early, consumed in epilogue

    // ---- x-phase (no dependency on other WGs; runs before the flag wait)
    const unsigned short* xp = xT + (size_t)t * (Bb * Hh) + aoff;
#pragma unroll
    for (int kf = 0; kf < 16; ++kf) {
      short8 a = *reinterpret_cast<const short8*>(xp + kf * 32);
      if (kf & 1) {
        acc01 = __builtin_amdgcn_mfma_f32_16x16x32_bf16(a, w[kf][0], acc01, 0, 0, 0);
        acc11 = __builtin_amdgcn_mfma_f32_16x16x32_bf16(a, w[kf][1], acc11, 0, 0, 0);
      } else {
        acc00 = __builtin_amdgcn_mfma_f32_16x16x32_bf16(a, w[kf][0], acc00, 0, 0, 0);
        acc10 = __builtin_amdgcn_mfma_f32_16x16x32_bf16(a, w[kf][1], acc10, 0, 0, 0);
      }
    }

    // ---- per-wave wait: all WGs have published h_{t-1} (flag >= t)
    if (t > 0) {
      unsigned tgt = (unsigned)t;
      int guard = 0;
      for (;;) {
        unsigned a = __hip_atomic_load(pf0, __ATOMIC_RELAXED, __HIP_MEMORY_SCOPE_AGENT);
        unsigned b = __hip_atomic_load(pf1, __ATOMIC_RELAXED, __HIP_MEMORY_SCOPE_AGENT);
        if (__all(a >= tgt && b >= tgt)) break;
        if (++guard > (1 << 16)) break;   // bounded: wrong answer, never a hang
      }
    }

    // ---- h-phase: agent-scope (L2-bypass) loads of h_{t-1}, then MFMAs
    const unsigned long long* hp8 = reinterpret_cast<const unsigned long long*>(
        hbuf + (size_t)((t & 1) ^ 1) * (Bb * Hh)) + (aoff >> 2);
    short8 hf[16];
#pragma unroll
    for (int kf = 0; kf < 16; ++kf) {
      U16 u;
      u.q[0] = __hip_atomic_load(hp8 + kf * 8,     __ATOMIC_RELAXED, __HIP_MEMORY_SCOPE_AGENT);
      u.q[1] = __hip_atomic_load(hp8 + kf * 8 + 1, __ATOMIC_RELAXED, __HIP_MEMORY_SCOPE_AGENT);
      hf[kf] = u.v;
    }
#pragma unroll
    for (int kf = 0; kf < 16; ++kf) {
      if (kf & 1) {
        acc01 = __builtin_amdgcn_mfma_f32_16x16x32_bf16(hf[kf], w[16 + kf][0], acc01, 0, 0, 0);
        acc11 = __builtin_amdgcn_mfma_f32_16x16x32_bf16(hf[kf], w[16 + kf][1], acc11, 0, 0, 0);
      } else {
        acc00 = __builtin_amdgcn_mfma_f32_16x16x32_bf16(hf[kf], w[16 + kf][0], acc00, 0, 0, 0);
        acc10 = __builtin_amdgcn_mfma_f32_16x16x32_bf16(hf[kf], w[16 + kf][1], acc10, 0, 0, 0);
      }
    }

    // ---- publish raw gate pre-activations to LDS (D-frag: row=(l>>4)*4+q, col=l&15)
    {
      f32x4 s0 = acc00 + acc01;
      f32x4 s1 = acc10 + acc11;
      int colbase = lane & 15;
      int row0 = wave * 16 + (lane >> 4) * 4;
#pragma unroll
      for (int q = 0; q < 4; ++q) g_lds[(row0 + q) * 33 + colbase] = s0[q];
#pragma unroll
      for (int q = 0; q < 4; ++q) g_lds[(row0 + q) * 33 + 16 + colbase] = s1[q];
    }
    __syncthreads();

    // ---- epilogue: thread (eb, er) consumes its 7 gates
    float gv[7];
#pragma unroll
    for (int g = 0; g < 7; ++g) gv[g] = g_lds[eb * 33 + g * 4 + er] + bs[g];

    float gi  = sigmoidf_(gv[0]);
    float gf  = sigmoidf_(gv[1]);
    float go  = sigmoidf_(gv[2]);
    float gib = sigmoidf_(gv[3]);
    float gfb = sigmoidf_(gv[4]);
    float gd  = softplusf_(gv[5]);
    float zt  = tanhf(gv[6]);

    float c_t    = gf * cf + gi * zt;
    float cbar_t = gfb * cb + gib * zt;
    float cfn    = cbar_t + (c_t - cbar_t) * expf(-gd * dt);
    float h      = go * tanhf(cfn);
    cf = cfn;
    cb = cbar_t;

    size_t ho = (size_t)(eb * Tt + t) * Hh + jcol;
    out[ho] = h;
    size_t db = (size_t)8388608 + (size_t)((eb * Tt + t) * 4) * Hh + jcol;
    out[db]        = c_t;
    out[db + 512]  = cbar_t;
    out[db + 1024] = gd;
    out[db + 1536] = go;

    // ---- pack 4 bf16 (er 0..3) into one 8B agent-scope store by er==0
    {
      unsigned hb16 = (unsigned)f2bf(h);
      unsigned other = (unsigned)__shfl_xor((int)hb16, 1);
      unsigned pair = hb16 | (other << 16);          // valid at even er
      unsigned pair_hi = (unsigned)__shfl_xor((int)pair, 2);
      if (er == 0) {
        unsigned long long v = (unsigned long long)pair |
                               ((unsigned long long)pair_hi << 32);
        unsigned long long* hw = reinterpret_cast<unsigned long long*>(
            hbuf + (size_t)(t & 1) * (Bb * Hh) + eb * Hh + wg * 4);
        __hip_atomic_store(hw, v, __ATOMIC_RELAXED, __HIP_MEMORY_SCOPE_AGENT);
      }
    }

    // ---- release: barrier drains vmcnt (sc1 stores at L3), then set flag
    __syncthreads();
    if (tid == 0) {
      __hip_atomic_store(flags + (size_t)wg * 16, (unsigned)(t + 1),
                         __ATOMIC_RELAXED, __HIP_MEMORY_SCOPE_AGENT);
    }
  }
}

extern "C" void kernel_launch(void* const* d_in, const int* in_sizes, int n_in,
                              void* d_out, int out_size, void* d_ws, size_t ws_size,
                              hipStream_t stream) {
  const float* X  = (const float*)d_in[0];   // [64][256][512]
  const float* dt = (const float*)d_in[1];   // [64][256]
  const float* W  = (const float*)d_in[2];   // [1024][3584]
  const float* bi = (const float*)d_in[3];   // [3584]
  float* out = (float*)d_out;

  char* ws = (char*)d_ws;
  unsigned short* wp   = (unsigned short*)(ws);             //  8,388,608 B
  unsigned short* xT   = (unsigned short*)(ws + 8388608);   // 16,777,216 B
  unsigned short* hb   = (unsigned short*)(ws + 25165824);  //    131,072 B
  unsigned int*  zbase = (unsigned int*)(ws + 25165824);    // hbuf + flags zero region
  unsigned int*  flg   = (unsigned int*)(ws + 25296896);    //      8,192 B

  k_pack_w<<<2048, 256, 0, stream>>>(W, wp);
  k_xt<<<8192, 256, 0, stream>>>(X, xT);
  k_init<<<64, 256, 0, stream>>>(zbase, 34816);
  k_seq<<<NWG, 256, 0, stream>>>(wp, xT, bi, dt, hb, flg, out);
}